// Round 9
// baseline (159.355 us; speedup 1.0000x reference)
//
#include <hip/hip_runtime.h>

typedef __attribute__((ext_vector_type(8))) short s16x8;
typedef __attribute__((ext_vector_type(4))) float f32x4;

union FragU {
    unsigned int u[4];
    uint4 v;
    s16x8 s;
};

// scale = 2^ceil(log2(max(ma,1e-12)))/128 ; returns 1/scale. Both exact pow2.
__device__ __forceinline__ float pow2_scale_inv(float ma, float& scale) {
    ma = fmaxf(ma, 1e-12f);
    unsigned u = __float_as_uint(ma);
    int E = (int)((u >> 23) & 255u);
    int ce = ((u & 0x7fffffu) == 0u) ? (E - 127) : (E - 126);  // ceil(log2(ma))
    int se = ce - 7;                                            // scale = 2^ce/128
    scale = __uint_as_float((unsigned)(se + 127) << 23);
    return __uint_as_float((unsigned)(127 - se) << 23);
}

// pack hi16 of two f32 bit patterns into one dword: [u1.hi16 : u0.hi16]
__device__ __forceinline__ unsigned pack_hi16(unsigned u0, unsigned u1) {
    return __builtin_amdgcn_perm(u1, u0, 0x07060302u);
}

// force a block-uniform float into an SGPR
__device__ __forceinline__ float uni(float x) {
    return __uint_as_float((unsigned)__builtin_amdgcn_readfirstlane(__float_as_uint(x)));
}

// lgkmcnt(0) drain + barrier, WITHOUT vmcnt drain (keeps prefetch in flight)
__device__ __forceinline__ void lds_barrier() {
    asm volatile("s_waitcnt lgkmcnt(0)" ::: "memory");
    __builtin_amdgcn_sched_barrier(0);
    __builtin_amdgcn_s_barrier();
    __builtin_amdgcn_sched_barrier(0);
}

__global__ __launch_bounds__(256, 2) void fused_kernel(
    const float* __restrict__ x,
    const float* __restrict__ W1,
    const float* __restrict__ b1,
    const float* __restrict__ W2,
    const float* __restrict__ b2,
    const float* __restrict__ Wo,
    const float* __restrict__ boutp,
    const float* __restrict__ a1p,
    const float* __restrict__ a2p,
    float* __restrict__ out,
    int ntiles) {

    // ~76 KB -> 2 blocks/CU (8 waves/CU). Block-cooperative tile, dbuf staging.
    __shared__ __align__(16) unsigned short w1f[16384];   // 32 KB: W1 frags
    __shared__ __align__(16) unsigned short w2f[4096];    //  8 KB: W2 frags
    __shared__ __align__(16) unsigned short stg[1024];    //  2 KB: h1q (block tile)
    __shared__ __align__(16) float partial[64];           // 256 B: L3 partials
    __shared__ __align__(16) unsigned int xb[2][4096];    // 32 KB: x tile dbuf
    __shared__ float redm[12];

    const int t = threadIdx.x;
    const int lane = t & 63;
    const int wv = t >> 6;

    // ============ weight prep, pass 1: max-abs scan (no retention) ============
    float m1 = 0.f, m2 = 0.f, mo = 0.f;
    #pragma unroll 4
    for (int k = 0; k < 16; ++k) {
        float4 v = *(const float4*)(W1 + 4 * (t + 256 * k));
        m1 = fmaxf(m1, fmaxf(fmaxf(fabsf(v.x), fabsf(v.y)),
                             fmaxf(fabsf(v.z), fabsf(v.w))));
    }
    #pragma unroll
    for (int k = 0; k < 4; ++k) {
        float4 v = *(const float4*)(W2 + 4 * (t + 256 * k));
        m2 = fmaxf(m2, fmaxf(fmaxf(fabsf(v.x), fabsf(v.y)),
                             fmaxf(fabsf(v.z), fabsf(v.w))));
    }
    if (t < 64) mo = fabsf(Wo[t]);

    #pragma unroll
    for (int m = 1; m < 64; m <<= 1) {
        m1 = fmaxf(m1, __shfl_xor(m1, m, 64));
        m2 = fmaxf(m2, __shfl_xor(m2, m, 64));
        mo = fmaxf(mo, __shfl_xor(mo, m, 64));
    }
    if (lane == 0) { redm[wv] = m1; redm[4 + wv] = m2; redm[8 + wv] = mo; }
    __syncthreads();
    m1 = fmaxf(fmaxf(redm[0], redm[1]), fmaxf(redm[2], redm[3]));
    m2 = fmaxf(fmaxf(redm[4], redm[5]), fmaxf(redm[6], redm[7]));
    mo = fmaxf(fmaxf(redm[8], redm[9]), fmaxf(redm[10], redm[11]));

    float s1v, s2v, sov;
    const float i1 = uni(pow2_scale_inv(m1, s1v));  // exact pow2
    const float i2 = uni(pow2_scale_inv(m2, s2v));
    const float io = uni(pow2_scale_inv(mo, sov));
    const float s1 = uni(s1v);

    const float a1 = uni(a1p[0]), a2 = uni(a2p[0]);
    const double d1 = 1.0 / (double)a1;
    const float i1h = uni((float)d1), i1l = uni((float)(d1 - (double)(float)d1));
    const double d2 = 1.0 / (double)a2;
    const float i2h = uni((float)d2), i2l = uni((float)(d2 - (double)(float)d2));

    // ============ weight prep, pass 2: reload (cache-hit) + quantize to LDS ===
    #pragma unroll 4
    for (int k = 0; k < 16; ++k) {
        const int i0 = 4 * (t + 256 * k);
        float4 v = *(const float4*)(W1 + i0);
        float q4[4] = {v.x, v.y, v.z, v.w};
        #pragma unroll
        for (int e = 0; e < 4; ++e) {
            const int i = i0 + e;
            float q = fminf(fmaxf(rintf(q4[e] * i1), -128.f), 127.f);
            const int u = i >> 8, kk = i & 255;
            const int c = u >> 4, ccb = u & 15, s = kk >> 5, gg = (kk >> 3) & 3, j = kk & 7;
            w1f[((s * 4 + c) * 64 + gg * 16 + ccb) * 8 + j] =
                (unsigned short)(__float_as_uint(q) >> 16);   // exact bf16 int
        }
    }
    #pragma unroll
    for (int k = 0; k < 4; ++k) {
        const int i0 = 4 * (t + 256 * k);
        float4 v = *(const float4*)(W2 + i0);
        float q4[4] = {v.x, v.y, v.z, v.w};
        #pragma unroll
        for (int e = 0; e < 4; ++e) {
            const int i = i0 + e;
            float q = fminf(fmaxf(rintf(q4[e] * i2), -128.f), 127.f);
            const int vv = i >> 6, kk = i & 63;
            const int c = vv >> 4, ccb = vv & 15, s = kk >> 5, gg = (kk >> 3) & 3, j = kk & 7;
            w2f[((s * 4 + c) * 64 + gg * 16 + ccb) * 8 + j] =
                (unsigned short)(__float_as_uint(q) >> 16);
        }
    }
    __syncthreads();

    // ============ main streaming loop (block-cooperative tiles) ==============
    const float boutv = uni(boutp[0]);
    const float c21 = uni(a1 * s2v);   // exact: s2 pow2
    const float c3  = uni(a2 * sov);   // exact: so pow2

    const int cc = lane & 15;    // row (L1 A-frag) / col-within-quarter (B,D)
    const int g  = lane >> 4;    // k-group / output row-group

    // this wave owns output-column quarter c = wv
    const float b1c = b1[wv * 16 + cc];
    const float b2c = b2[wv * 16 + cc];
    const float wqc = fminf(fmaxf(rintf(Wo[wv * 16 + cc] * io), -128.f), 127.f);

    // swizzled frag-read offsets (R8 hardware-verified involution)
    const int xo0 = cc * 1024 + (((2 * g + 0 + cc) & 7) << 4);
    const int xo1 = cc * 1024 + (((2 * g + 1 + cc) & 7) << 4);
    const int lreg = (lane >> 3) << 7;   // staging source 128B region

    // --- chunked work assignment: XCD-affine, contiguous chunk per block -----
    const int b = blockIdx.x;
    const int nb = gridDim.x;
    const int pb = (nb & 7) ? b : ((b & 7) * (nb >> 3) + (b >> 3));
    const int S = (int)(((long long)pb * ntiles) / nb);
    const int E = (int)(((long long)(pb + 1) * ntiles) / nb);

    // prologue: stage first tile (4 contiguous-1KB gload_lds per wave)
    if (S < E) {
        const char* gs = (const char*)(x + (size_t)S * 4096);
        #pragma unroll
        for (int r4 = 0; r4 < 4; ++r4) {
            const int r = wv * 4 + r4;
            const int so = lreg + (((lane - r) & 7) << 4);   // inverse swizzle
            __builtin_amdgcn_global_load_lds(
                (const unsigned int*)(gs + r * 1024 + so), &xb[0][r * 256], 16, 0, 0);
        }
    }
    asm volatile("s_waitcnt vmcnt(0)" ::: "memory");
    __builtin_amdgcn_sched_barrier(0);
    __builtin_amdgcn_s_barrier();
    __builtin_amdgcn_sched_barrier(0);

    for (int tile = S; tile < E; ++tile) {
        const int cur = (tile - S) & 1;

        // stage NEXT tile into the other buffer (full tile period to land)
        if (tile + 1 < E) {
            const char* gs = (const char*)(x + (size_t)(tile + 1) * 4096);
            #pragma unroll
            for (int r4 = 0; r4 < 4; ++r4) {
                const int r = wv * 4 + r4;
                const int so = lreg + (((lane - r) & 7) << 4);
                __builtin_amdgcn_global_load_lds(
                    (const unsigned int*)(gs + r * 1024 + so),
                    &xb[cur ^ 1][r * 256], 16, 0, 0);
            }
        }

        const char* xbc = (const char*)xb[cur];
        f32x4 acc = (f32x4){0.f, 0.f, 0.f, 0.f};

        #pragma unroll
        for (int ks = 0; ks < 8; ++ks) {
            const float4 A = *(const float4*)(xbc + xo0 + ks * 128);  // ds_read_b128
            const float4 B = *(const float4*)(xbc + xo1 + ks * 128);

            // exact 3-way bf16 split: x = hi + lo + lo2 (v_perm packing)
            float f[8] = {A.x, A.y, A.z, A.w, B.x, B.y, B.z, B.w};
            FragU hi, lo, lo2;
            #pragma unroll
            for (int p = 0; p < 4; ++p) {
                const float f0 = f[2 * p], f1 = f[2 * p + 1];
                const unsigned u0 = __float_as_uint(f0), u1 = __float_as_uint(f1);
                hi.u[p] = pack_hi16(u0, u1);
                const float r0 = f0 - __uint_as_float(u0 & 0xffff0000u);
                const float r1 = f1 - __uint_as_float(u1 & 0xffff0000u);
                const unsigned v0 = __float_as_uint(r0), v1 = __float_as_uint(r1);
                lo.u[p] = pack_hi16(v0, v1);
                const float q0 = r0 - __uint_as_float(v0 & 0xffff0000u);
                const float q1 = r1 - __uint_as_float(v1 & 0xffff0000u);
                lo2.u[p] = pack_hi16(__float_as_uint(q0), __float_as_uint(q1));
            }
            // this wave's c-quarter only (c = wv): 3 MFMA per ks
            FragU bb;
            bb.v = *(const uint4*)&w1f[((ks * 4 + wv) * 64 + lane) * 8];
            acc = __builtin_amdgcn_mfma_f32_16x16x32_bf16(hi.s,  bb.s, acc, 0, 0, 0);
            acc = __builtin_amdgcn_mfma_f32_16x16x32_bf16(lo.s,  bb.s, acc, 0, 0, 0);
            acc = __builtin_amdgcn_mfma_f32_16x16x32_bf16(lo2.s, bb.s, acc, 0, 0, 0);
        }

        // ---- layer-1 epilogue (c = wv): quant-relu -> shared A-frag staging --
        #pragma unroll
        for (int j = 0; j < 4; ++j) {
            float h = fmaf(acc[j], s1, b1c);         // acc*s1 exact (pow2)
            h = fmaxf(h, 0.f);
            float n = rintf(fmaf(h, i1l, h * i1h));  // DF-recip divide
            n = fminf(n, 255.f);
            const int r = g * 4 + j;
            const int u = wv * 16 + cc;
            const int pos = ((u >> 5) * 64 + ((u >> 3) & 3) * 16 + r) * 8 + (u & 7);
            stg[pos] = (unsigned short)(__float_as_uint(n) >> 16);  // exact bf16 int
        }
        lds_barrier();   // h1q complete (no vmcnt drain)

        s16x8 afrag[2];
        #pragma unroll
        for (int s = 0; s < 2; ++s) {
            FragU a;
            a.v = *(const uint4*)&stg[(s * 64 + lane) * 8];
            afrag[s] = a.s;
        }

        f32x4 acc2 = (f32x4){0.f, 0.f, 0.f, 0.f};
        #pragma unroll
        for (int s = 0; s < 2; ++s) {
            FragU bb;
            bb.v = *(const uint4*)&w2f[((s * 4 + wv) * 64 + lane) * 8];
            acc2 = __builtin_amdgcn_mfma_f32_16x16x32_bf16(afrag[s], bb.s, acc2, 0, 0, 0);
        }

        // ---- layer-2 epilogue + layer-3 partial (integer-exact) --------------
        float psum[4];
        #pragma unroll
        for (int j = 0; j < 4; ++j) {
            float h = fmaf(acc2[j], c21, b2c);
            h = fmaxf(h, 0.f);
            float n = rintf(fmaf(h, i2l, h * i2h));  // DF-recip divide
            n = fminf(n, 255.f);
            psum[j] = n * wqc;                        // exact int product
        }
        #pragma unroll
        for (int j = 0; j < 4; ++j) {
            #pragma unroll
            for (int mask = 1; mask < 16; mask <<= 1)
                psum[j] += __shfl_xor(psum[j], mask, 16);  // exact int adds
        }
        if (cc == 0) {
            float4 pw = {psum[0], psum[1], psum[2], psum[3]};
            *(float4*)&partial[wv * 16 + g * 4] = pw;
        }
        lds_barrier();   // partials ready

        float oval = 0.f;
        if (wv == 0 && lane < 16) {
            oval = (partial[lane] + partial[16 + lane]) +
                   (partial[32 + lane] + partial[48 + lane]);   // exact ints
            oval = fmaf(oval, c3, boutv);
        }

        // gate: own 4 gloads for next buffer landed; then block-wide ready
        asm volatile("s_waitcnt vmcnt(0)" ::: "memory");
        __builtin_amdgcn_sched_barrier(0);
        __builtin_amdgcn_s_barrier();
        __builtin_amdgcn_sched_barrier(0);

        // store after the gate so its completion never stalls the barrier
        if (wv == 0 && lane < 16) out[(size_t)tile * 16 + lane] = oval;
    }
}

extern "C" void kernel_launch(void* const* d_in, const int* in_sizes, int n_in,
                              void* d_out, int out_size, void* d_ws, size_t ws_size,
                              hipStream_t stream) {
    const float* x    = (const float*)d_in[0];
    const float* W1   = (const float*)d_in[1];
    const float* b1   = (const float*)d_in[2];
    const float* W2   = (const float*)d_in[3];
    const float* b2   = (const float*)d_in[4];
    const float* Wout = (const float*)d_in[5];
    const float* bout = (const float*)d_in[6];
    const float* a1   = (const float*)d_in[7];
    const float* a2   = (const float*)d_in[8];
    float* out = (float*)d_out;

    const int rows = in_sizes[0] / 256;
    const int ntiles = rows / 16;            // 31250 for B=500000

    int blocks = 512;                         // 2 blocks/CU, ~61 tiles/block
    if (blocks > ntiles) blocks = ntiles;     // tiny-N fallback
    fused_kernel<<<blocks, 256, 0, stream>>>(x, W1, b1, W2, b2, Wout, bout,
                                             a1, a2, out, ntiles);
}

// Round 10
// 106.692 us; speedup vs baseline: 1.4936x; 1.4936x over previous
//
#include <hip/hip_runtime.h>

typedef __attribute__((ext_vector_type(8))) short s16x8;
typedef __attribute__((ext_vector_type(4))) float f32x4;

union FragU {
    unsigned int u[4];
    uint4 v;
    s16x8 s;
};

// scale = 2^ceil(log2(max(ma,1e-12)))/128 ; returns 1/scale. Both exact pow2.
__device__ __forceinline__ float pow2_scale_inv(float ma, float& scale) {
    ma = fmaxf(ma, 1e-12f);
    unsigned u = __float_as_uint(ma);
    int E = (int)((u >> 23) & 255u);
    int ce = ((u & 0x7fffffu) == 0u) ? (E - 127) : (E - 126);  // ceil(log2(ma))
    int se = ce - 7;                                            // scale = 2^ce/128
    scale = __uint_as_float((unsigned)(se + 127) << 23);
    return __uint_as_float((unsigned)(127 - se) << 23);
}

// pack hi16 of two f32 bit patterns into one dword: [u1.hi16 : u0.hi16]
__device__ __forceinline__ unsigned pack_hi16(unsigned u0, unsigned u1) {
    return __builtin_amdgcn_perm(u1, u0, 0x07060302u);
}

// force a block-uniform float into an SGPR
__device__ __forceinline__ float uni(float x) {
    return __uint_as_float((unsigned)__builtin_amdgcn_readfirstlane(__float_as_uint(x)));
}

__global__ __launch_bounds__(512, 4) void fused_kernel(
    const float* __restrict__ x,
    const float* __restrict__ W1,
    const float* __restrict__ b1,
    const float* __restrict__ W2,
    const float* __restrict__ b2,
    const float* __restrict__ Wo,
    const float* __restrict__ boutp,
    const float* __restrict__ a1p,
    const float* __restrict__ a2p,
    float* __restrict__ out,
    int ntiles, int nwaves) {

    // 56.1 KB total -> 2 blocks/CU, 8 waves share one weight image
    __shared__ __align__(16) unsigned short w1f[16384];     // 32 KB: W1 frags
    __shared__ __align__(16) unsigned short w2f[4096];      //  8 KB: W2 frags
    __shared__ __align__(16) unsigned short stg[8][1024];   // 16 KB: per-wave h1q staging
    __shared__ float redm[24];

    const int t = threadIdx.x;
    const int lane = t & 63;
    const int wv = t >> 6;

    // ============ weight prep, pass 1: max-abs scan (no retention) ============
    float m1 = 0.f, m2 = 0.f, mo = 0.f;
    #pragma unroll 4
    for (int k = 0; k < 8; ++k) {
        float4 v = *(const float4*)(W1 + 4 * (t + 512 * k));
        m1 = fmaxf(m1, fmaxf(fmaxf(fabsf(v.x), fabsf(v.y)),
                             fmaxf(fabsf(v.z), fabsf(v.w))));
    }
    #pragma unroll
    for (int k = 0; k < 2; ++k) {
        float4 v = *(const float4*)(W2 + 4 * (t + 512 * k));
        m2 = fmaxf(m2, fmaxf(fmaxf(fabsf(v.x), fabsf(v.y)),
                             fmaxf(fabsf(v.z), fabsf(v.w))));
    }
    if (t < 64) mo = fabsf(Wo[t]);

    #pragma unroll
    for (int m = 1; m < 64; m <<= 1) {
        m1 = fmaxf(m1, __shfl_xor(m1, m, 64));
        m2 = fmaxf(m2, __shfl_xor(m2, m, 64));
        mo = fmaxf(mo, __shfl_xor(mo, m, 64));
    }
    if (lane == 0) { redm[wv] = m1; redm[8 + wv] = m2; redm[16 + wv] = mo; }
    __syncthreads();
    m1 = fmaxf(fmaxf(fmaxf(redm[0], redm[1]), fmaxf(redm[2], redm[3])),
               fmaxf(fmaxf(redm[4], redm[5]), fmaxf(redm[6], redm[7])));
    m2 = fmaxf(fmaxf(fmaxf(redm[8], redm[9]), fmaxf(redm[10], redm[11])),
               fmaxf(fmaxf(redm[12], redm[13]), fmaxf(redm[14], redm[15])));
    mo = fmaxf(fmaxf(fmaxf(redm[16], redm[17]), fmaxf(redm[18], redm[19])),
               fmaxf(fmaxf(redm[20], redm[21]), fmaxf(redm[22], redm[23])));

    float s1v, s2v, sov;
    const float i1 = uni(pow2_scale_inv(m1, s1v));  // exact pow2
    const float i2 = uni(pow2_scale_inv(m2, s2v));
    const float io = uni(pow2_scale_inv(mo, sov));
    const float s1 = uni(s1v);

    const float a1 = uni(a1p[0]), a2 = uni(a2p[0]);
    // double-float reciprocals of a1, a2 (quotient err <= ~1 ulp)
    const double d1 = 1.0 / (double)a1;
    const float i1h = uni((float)d1), i1l = uni((float)(d1 - (double)(float)d1));
    const double d2 = 1.0 / (double)a2;
    const float i2h = uni((float)d2), i2l = uni((float)(d2 - (double)(float)d2));

    // ============ weight prep, pass 2: reload (L2-hit) + quantize to LDS ======
    // W1 packed with sector-contiguous sigma: slot j of lane-group gg holds
    //   k = s*32 + (j<4 ? gg*4+j : 16+gg*4+(j-4))
    // matching the new x-load mapping (A and B permuted identically).
    #pragma unroll 4
    for (int k = 0; k < 8; ++k) {
        const int i0 = 4 * (t + 512 * k);
        float4 v = *(const float4*)(W1 + i0);
        float q4[4] = {v.x, v.y, v.z, v.w};
        #pragma unroll
        for (int e = 0; e < 4; ++e) {
            const int i = i0 + e;
            float q = fminf(fmaxf(rintf(q4[e] * i1), -128.f), 127.f);
            const int u = i >> 8, kk = i & 255;
            const int c = u >> 4, ccb = u & 15;
            const int s = kk >> 5, r = kk & 31;
            const int gg = (r & 15) >> 2;
            const int j = ((r >> 4) << 2) + (r & 3);
            w1f[((s * 4 + c) * 64 + gg * 16 + ccb) * 8 + j] =
                (unsigned short)(__float_as_uint(q) >> 16);   // exact bf16 int
        }
    }
    #pragma unroll
    for (int k = 0; k < 2; ++k) {
        const int i0 = 4 * (t + 512 * k);
        float4 v = *(const float4*)(W2 + i0);
        float q4[4] = {v.x, v.y, v.z, v.w};
        #pragma unroll
        for (int e = 0; e < 4; ++e) {
            const int i = i0 + e;
            float q = fminf(fmaxf(rintf(q4[e] * i2), -128.f), 127.f);
            const int vv = i >> 6, kk = i & 63;
            const int c = vv >> 4, ccb = vv & 15, s = kk >> 5, gg = (kk >> 3) & 3, j = kk & 7;
            w2f[((s * 4 + c) * 64 + gg * 16 + ccb) * 8 + j] =
                (unsigned short)(__float_as_uint(q) >> 16);   // old sigma (layer 2)
        }
    }
    __syncthreads();

    // ============ main streaming loop =========================================
    const float boutv = uni(boutp[0]);
    const float c21 = uni(a1 * s2v);   // exact: s2 pow2
    const float c3  = uni(a2 * sov);   // exact: so pow2

    const int cc = lane & 15;    // row-within-tile (A) / col (B,D)
    const int g  = lane >> 4;    // k-group / D row-group

    float b1c[4], b2c[4], wqc[4];
    #pragma unroll
    for (int c = 0; c < 4; ++c) {
        b1c[c] = b1[c * 16 + cc];
        b2c[c] = b2[c * 16 + cc];
        wqc[c] = fminf(fmaxf(rintf(Wo[c * 16 + cc] * io), -128.f), 127.f);
    }

    unsigned short* st = stg[wv];
    const int gw0 = blockIdx.x * 8 + wv;

    // software pipeline: 8 float4 slots = 4 k-steps ahead.
    // Sector-contiguous loads: lane (cc,g): loadA = row cc, bytes [ks*128 + g*16)
    // (full 64B sector across g=0..3), loadB = +64B (the other sector).
    float4 xv[8];
    if (gw0 < ntiles) {
        const float* xp0 = x + (size_t)(gw0 * 16 + cc) * 256 + g * 4;
        #pragma unroll
        for (int s = 0; s < 4; ++s) {
            xv[2 * s]     = *(const float4*)(xp0 + s * 32);
            xv[2 * s + 1] = *(const float4*)(xp0 + s * 32 + 16);
        }
    }

    for (int tile = gw0; tile < ntiles; tile += nwaves) {
        const float* xp = x + (size_t)(tile * 16 + cc) * 256 + g * 4;
        const int nt = tile + nwaves;
        const bool pf = nt < ntiles;                         // wave-uniform
        const float* xpn = pf ? (x + (size_t)(nt * 16 + cc) * 256 + g * 4) : xp;

        f32x4 acc[4];
        #pragma unroll
        for (int c = 0; c < 4; ++c) acc[c] = (f32x4){0.f, 0.f, 0.f, 0.f};

        #pragma unroll
        for (int ks = 0; ks < 8; ++ks) {
            const int sl = ks & 3;
            const float4 A = xv[2 * sl];
            const float4 B = xv[2 * sl + 1];

            // refill slot with data 4 k-steps ahead (crosses into next tile)
            const float* pb_ = (ks < 4) ? (xp + (ks + 4) * 32) : (xpn + (ks - 4) * 32);
            xv[2 * sl]     = *(const float4*)(pb_);
            xv[2 * sl + 1] = *(const float4*)(pb_ + 16);

            // exact 3-way bf16 split: x = hi + lo + lo2 (v_perm packing)
            float f[8] = {A.x, A.y, A.z, A.w, B.x, B.y, B.z, B.w};
            FragU hi, lo, lo2;
            #pragma unroll
            for (int p = 0; p < 4; ++p) {
                const float f0 = f[2 * p], f1 = f[2 * p + 1];
                const unsigned u0 = __float_as_uint(f0), u1 = __float_as_uint(f1);
                hi.u[p] = pack_hi16(u0, u1);
                const float r0 = f0 - __uint_as_float(u0 & 0xffff0000u);
                const float r1 = f1 - __uint_as_float(u1 & 0xffff0000u);
                const unsigned v0 = __float_as_uint(r0), v1 = __float_as_uint(r1);
                lo.u[p] = pack_hi16(v0, v1);
                const float q0 = r0 - __uint_as_float(v0 & 0xffff0000u);
                const float q1 = r1 - __uint_as_float(v1 & 0xffff0000u);
                lo2.u[p] = pack_hi16(__float_as_uint(q0), __float_as_uint(q1));
            }
            #pragma unroll
            for (int c = 0; c < 4; ++c) {
                FragU bb;
                bb.v = *(const uint4*)&w1f[((ks * 4 + c) * 64 + lane) * 8];
                acc[c] = __builtin_amdgcn_mfma_f32_16x16x32_bf16(hi.s,  bb.s, acc[c], 0, 0, 0);
                acc[c] = __builtin_amdgcn_mfma_f32_16x16x32_bf16(lo.s,  bb.s, acc[c], 0, 0, 0);
                acc[c] = __builtin_amdgcn_mfma_f32_16x16x32_bf16(lo2.s, bb.s, acc[c], 0, 0, 0);
            }
        }

        // ---- layer-1 epilogue: quant-relu -> A-frag staging (wave-private) ----
        #pragma unroll
        for (int c = 0; c < 4; ++c) {
            #pragma unroll
            for (int j = 0; j < 4; ++j) {
                float h = fmaf(acc[c][j], s1, b1c[c]);   // acc*s1 exact (pow2)
                h = fmaxf(h, 0.f);
                float n = rintf(fmaf(h, i1l, h * i1h));  // DF-recip divide
                n = fminf(n, 255.f);
                const int r = g * 4 + j;
                const int u = c * 16 + cc;
                const int pos = ((u >> 5) * 64 + ((u >> 3) & 3) * 16 + r) * 8 + (u & 7);
                st[pos] = (unsigned short)(__float_as_uint(n) >> 16);  // exact bf16 int
            }
        }
        asm volatile("s_waitcnt lgkmcnt(0)" ::: "memory");  // wave-private: no barrier

        s16x8 afrag[2];
        #pragma unroll
        for (int s = 0; s < 2; ++s) {
            FragU a;
            a.v = *(const uint4*)&st[(s * 64 + lane) * 8];
            afrag[s] = a.s;
        }

        f32x4 acc2[4];
        #pragma unroll
        for (int c = 0; c < 4; ++c) acc2[c] = (f32x4){0.f, 0.f, 0.f, 0.f};
        #pragma unroll
        for (int s = 0; s < 2; ++s) {
            #pragma unroll
            for (int c = 0; c < 4; ++c) {
                FragU bb;
                bb.v = *(const uint4*)&w2f[((s * 4 + c) * 64 + lane) * 8];
                acc2[c] = __builtin_amdgcn_mfma_f32_16x16x32_bf16(afrag[s], bb.s, acc2[c], 0, 0, 0);
            }
        }

        // ---- layer-2 epilogue + layer-3 dot (integer-exact accumulation) ----
        float psum[4] = {0.f, 0.f, 0.f, 0.f};
        #pragma unroll
        for (int c = 0; c < 4; ++c) {
            #pragma unroll
            for (int j = 0; j < 4; ++j) {
                float h = fmaf(acc2[c][j], c21, b2c[c]);
                h = fmaxf(h, 0.f);
                float n = rintf(fmaf(h, i2l, h * i2h));  // DF-recip divide
                n = fminf(n, 255.f);
                psum[j] = fmaf(n, wqc[c], psum[j]);      // exact int accumulation
            }
        }
        #pragma unroll
        for (int j = 0; j < 4; ++j) {
            #pragma unroll
            for (int mask = 1; mask < 16; mask <<= 1)
                psum[j] += __shfl_xor(psum[j], mask, 16);
        }

        if (cc == 0) {
            float4 o;
            o.x = fmaf(psum[0], c3, boutv);
            o.y = fmaf(psum[1], c3, boutv);
            o.z = fmaf(psum[2], c3, boutv);
            o.w = fmaf(psum[3], c3, boutv);
            *(float4*)(out + (size_t)tile * 16 + g * 4) = o;
        }
    }
}

extern "C" void kernel_launch(void* const* d_in, const int* in_sizes, int n_in,
                              void* d_out, int out_size, void* d_ws, size_t ws_size,
                              hipStream_t stream) {
    const float* x    = (const float*)d_in[0];
    const float* W1   = (const float*)d_in[1];
    const float* b1   = (const float*)d_in[2];
    const float* W2   = (const float*)d_in[3];
    const float* b2   = (const float*)d_in[4];
    const float* Wout = (const float*)d_in[5];
    const float* bout = (const float*)d_in[6];
    const float* a1   = (const float*)d_in[7];
    const float* a2   = (const float*)d_in[8];
    float* out = (float*)d_out;

    const int rows = in_sizes[0] / 256;
    const int ntiles = rows / 16;            // 31250 for B=500000

    int blocks = 512;                         // 2 blocks/CU, 4 waves/SIMD
    if (blocks * 8 > ntiles) blocks = (ntiles + 7) / 8;
    const int nwaves = blocks * 8;

    fused_kernel<<<blocks, 512, 0, stream>>>(x, W1, b1, W2, b2, Wout, bout,
                                             a1, a2, out, ntiles, nwaves);
}